// Round 23
// baseline (106.922 us; speedup 1.0000x reference)
//
#include <hip/hip_runtime.h>
#include <cstdint>
#include <cstddef>

#define NE 1024   // embedding dim
#define HS 64     // head size
#define TT 2048   // sequence length
#define BB 8      // batch

typedef short bf16x8 __attribute__((ext_vector_type(8)));
typedef float f32x4  __attribute__((ext_vector_type(4)));

// round-to-nearest-even f32 -> bf16 (bit pattern as ushort)
__device__ __forceinline__ unsigned short f2b(float f) {
    union { float f; uint32_t u; } v; v.f = f;
    uint32_t r = v.u + 0x7fffu + ((v.u >> 16) & 1u);
    return (unsigned short)(r >> 16);
}
__device__ __forceinline__ float b2f(unsigned short b) {
    union { uint32_t u; float f; } v; v.u = ((uint32_t)b) << 16;
    return v.f;
}

// ---------------------------------------------------------------------------
// Kernel 0: W = [Wq;Wk;Wv*0.125] (192x1024) -> MFMA B-fragments, split hi/lo.
// frag layout (16x16x32): lane L holds B[k=kcg*32+(L>>4)*8+j][col=ntg*16+(L&15)]
// ---------------------------------------------------------------------------
__global__ __launch_bounds__(256) void wprep_kernel(
    const float* __restrict__ Wq, const float* __restrict__ Wk,
    const float* __restrict__ Wv,
    unsigned short* __restrict__ whf, unsigned short* __restrict__ wlf)
{
    const int t   = blockIdx.x * 256 + threadIdx.x;   // 0..24575
    const int L   = t & 63;
    const int kcg = (t >> 6) & 31;
    const int ntg = t >> 11;                          // 0..11
    const int col = ntg * 16 + (L & 15);              // 0..191
    const int k0  = kcg * 32 + (L >> 4) * 8;

    const float* W;
    float scale = 1.f;
    if (col < 64)        W = Wq + (size_t)col * NE;
    else if (col < 128)  W = Wk + (size_t)(col - 64) * NE;
    else               { W = Wv + (size_t)(col - 128) * NE; scale = 0.125f; }

    bf16x8 h, l;
#pragma unroll
    for (int j = 0; j < 8; ++j) {
        const float f = W[k0 + j] * scale;
        const unsigned short hb = f2b(f);
        const unsigned short lb = f2b(f - b2f(hb));
        h[j] = (short)hb;
        l[j] = (short)lb;
    }
    *reinterpret_cast<bf16x8*>(whf + (size_t)t * 8) = h;
    *reinterpret_cast<bf16x8*>(wlf + (size_t)t * 8) = l;
}

// ---------------------------------------------------------------------------
// Kernel 1: projections via split-bf16 MFMA — BK=128 (round-18 champion):
// 8 K-iterations, 16 barrier crossings; each MFMA phase is 72 MFMAs +
// 24 frag loads between syncs. LDS 16 KB; 2 blocks/CU (4 waves/SIMD).
// BM=32, 256 threads = 4 waves, grid 512.
// ---------------------------------------------------------------------------
__global__ __launch_bounds__(256) void proj_mfma(
    const float* __restrict__ x,
    const unsigned short* __restrict__ whf,
    const unsigned short* __restrict__ wlf,
    unsigned short* __restrict__ qh, unsigned short* __restrict__ ql,
    unsigned short* __restrict__ kh, unsigned short* __restrict__ kl,
    unsigned short* __restrict__ vT)
{
    __shared__ unsigned short xh[32 * 128];  // 8 KB, swizzled
    __shared__ unsigned short xl[32 * 128];  // 8 KB, swizzled

    const int tid  = threadIdx.x;
    const int L    = tid & 63;
    const int w    = tid >> 6;               // wave id 0..3
    const int g    = L >> 4;
    const int l16  = L & 15;
    const int row0 = blockIdx.x * 32;
    const int ntgb = w * 3;                  // n-tile-group base: 0,3,6,9

    f32x4 acc[2][3];
#pragma unroll
    for (int mt = 0; mt < 2; ++mt)
#pragma unroll
        for (int nt = 0; nt < 3; ++nt)
#pragma unroll
            for (int r = 0; r < 4; ++r) acc[mt][nt][r] = 0.f;

    // staging: 32x128 tile = 512 8-float chunks; thread covers chunks
    // c = tid, tid+256 -> row = c>>4, col8 = c&15 (coalesced float4 pairs)
    const int srow0 = tid >> 4;              // 0..15  (chunk tid)
    const int scol0 = tid & 15;
    const int srow1 = (tid + 256) >> 4;      // 16..31 (chunk tid+256)
    const int scol1 = scol0;
    const float* xsrc0 = x + (size_t)(row0 + srow0) * NE + scol0 * 8;
    const float* xsrc1 = x + (size_t)(row0 + srow1) * NE + scol1 * 8;
    const int soff0 = srow0 * 128 + ((scol0 ^ (srow0 & 7)) << 3);
    const int soff1 = srow1 * 128 + ((scol1 ^ (srow1 & 7)) << 3);

    // prefetch ks = 0
    float4 p0 = *reinterpret_cast<const float4*>(xsrc0);
    float4 p1 = *reinterpret_cast<const float4*>(xsrc0 + 4);
    float4 p2 = *reinterpret_cast<const float4*>(xsrc1);
    float4 p3 = *reinterpret_cast<const float4*>(xsrc1 + 4);

    for (int ks = 0; ks < 8; ++ks) {         // K loop, BK = 128
        __syncthreads();                     // prior-step LDS reads done
        {
            float xv[8];
            bf16x8 hv, lv;
            xv[0]=p0.x; xv[1]=p0.y; xv[2]=p0.z; xv[3]=p0.w;
            xv[4]=p1.x; xv[5]=p1.y; xv[6]=p1.z; xv[7]=p1.w;
#pragma unroll
            for (int j = 0; j < 8; ++j) {
                const unsigned short hb = f2b(xv[j]);
                const unsigned short lb = f2b(xv[j] - b2f(hb));
                hv[j] = (short)hb; lv[j] = (short)lb;
            }
            *reinterpret_cast<bf16x8*>(&xh[soff0]) = hv;
            *reinterpret_cast<bf16x8*>(&xl[soff0]) = lv;
            xv[0]=p2.x; xv[1]=p2.y; xv[2]=p2.z; xv[3]=p2.w;
            xv[4]=p3.x; xv[5]=p3.y; xv[6]=p3.z; xv[7]=p3.w;
#pragma unroll
            for (int j = 0; j < 8; ++j) {
                const unsigned short hb = f2b(xv[j]);
                const unsigned short lb = f2b(xv[j] - b2f(hb));
                hv[j] = (short)hb; lv[j] = (short)lb;
            }
            *reinterpret_cast<bf16x8*>(&xh[soff1]) = hv;
            *reinterpret_cast<bf16x8*>(&xl[soff1]) = lv;
        }
        if (ks < 7) {                        // prefetch next subtile
            p0 = *reinterpret_cast<const float4*>(xsrc0 + (ks + 1) * 128);
            p1 = *reinterpret_cast<const float4*>(xsrc0 + (ks + 1) * 128 + 4);
            p2 = *reinterpret_cast<const float4*>(xsrc1 + (ks + 1) * 128);
            p3 = *reinterpret_cast<const float4*>(xsrc1 + (ks + 1) * 128 + 4);
        }
        __syncthreads();

#pragma unroll
        for (int kc = 0; kc < 4; ++kc) {     // four K=32 chunks per step
            bf16x8 ah[2], al[2];
#pragma unroll
            for (int mt = 0; mt < 2; ++mt) {
                const int r    = mt * 16 + l16;
                const int kb16 = kc * 4 + g;
                const int off  = r * 128 + ((kb16 ^ (r & 7)) << 3);
                ah[mt] = *reinterpret_cast<const bf16x8*>(&xh[off]);
                al[mt] = *reinterpret_cast<const bf16x8*>(&xl[off]);
            }
#pragma unroll
            for (int nt = 0; nt < 3; ++nt) {
                const size_t fidx =
                    ((size_t)((ntgb + nt) * 32 + (ks * 4 + kc))) * 64 + L;
                const bf16x8 bh = *reinterpret_cast<const bf16x8*>(whf + fidx * 8);
                const bf16x8 bl = *reinterpret_cast<const bf16x8*>(wlf + fidx * 8);
#pragma unroll
                for (int mt = 0; mt < 2; ++mt) {
                    acc[mt][nt] = __builtin_amdgcn_mfma_f32_16x16x32_bf16(
                        ah[mt], bh, acc[mt][nt], 0, 0, 0);
                    acc[mt][nt] = __builtin_amdgcn_mfma_f32_16x16x32_bf16(
                        ah[mt], bl, acc[mt][nt], 0, 0, 0);
                    acc[mt][nt] = __builtin_amdgcn_mfma_f32_16x16x32_bf16(
                        al[mt], bh, acc[mt][nt], 0, 0, 0);
                }
            }
        }
    }

    // epilogue: C/D layout col=L&15, row=(L>>4)*4+reg
#pragma unroll
    for (int nt = 0; nt < 3; ++nt) {
        const int gc0 = (ntgb + nt) * 16;
        const int lc  = l16;
#pragma unroll
        for (int mt = 0; mt < 2; ++mt) {
            const int t0g = row0 + mt * 16 + g * 4;   // row of reg 0
            if (gc0 < 128) {
                unsigned short* dh = (gc0 < 64) ? qh : kh;
                unsigned short* dl = (gc0 < 64) ? ql : kl;
                const int col = (gc0 & 63) + lc;
#pragma unroll
                for (int reg = 0; reg < 4; ++reg) {
                    const float val = acc[mt][nt][reg];
                    const unsigned short hb = f2b(val);
                    const unsigned short lb = f2b(val - b2f(hb));
                    dh[(size_t)(t0g + reg) * HS + col] = hb;
                    dl[(size_t)(t0g + reg) * HS + col] = lb;
                }
            } else {
                const int col  = (gc0 - 128) + lc;   // h index
                const int bat  = t0g >> 11;
                const int tloc = t0g & 2047;
                ushort4 pk;
                unsigned short* pp = reinterpret_cast<unsigned short*>(&pk);
#pragma unroll
                for (int reg = 0; reg < 4; ++reg)
                    pp[reg] = f2b(acc[mt][nt][reg]);
                *reinterpret_cast<ushort4*>(
                    &vT[((size_t)bat * HS + col) * TT + tloc]) = pk;
            }
        }
    }
}

// ---------------------------------------------------------------------------
// Kernel 2: MFMA causal attention — round-21 champion + pipelined QK^T
// K-loads: loads are UNCONDITIONAL and double-buffered (static i&1 regs),
// so iteration i+1's fragment loads issue while iteration i's MFMAs run —
// no per-iteration L2 latency exposure behind the wave-uniform E-branch.
// Only the MFMA clusters stay guarded. Beyond-E loads hit valid memory
// (full-T arrays) and cost only L2 BW in cheap tail blocks.
// QBLK=32, 512 thr = 8 waves, descending qt (LPT), no max-sub, early
// zero-fill, scattered A stores fused with P-write, PV last with 2 accs,
// setprio around MFMA clusters.
// ---------------------------------------------------------------------------
__global__ __launch_bounds__(512, 2) void attn_mfma(
    const unsigned short* __restrict__ qh, const unsigned short* __restrict__ ql,
    const unsigned short* __restrict__ kh, const unsigned short* __restrict__ kl,
    const unsigned short* __restrict__ vT,
    float* __restrict__ A, float* __restrict__ out)
{
    __shared__ unsigned short P[32 * TT];    // 128 KB, 16B-chunk XOR swizzle
    __shared__ float reds[8][32];
    __shared__ float sinv[32];

    const int tid = threadIdx.x;
    const int L   = tid & 63;
    const int w   = tid >> 6;                // wave 0..7
    const int b   = blockIdx.x & 7;          // batch == XCD slot
    const int qt  = 63 - (blockIdx.x >> 3);  // longest first (LPT)
    const int Q0  = qt * 32;
    const int E   = Q0 + 32;                 // causal extent (mult of 32)
    const int g   = L >> 4;
    const int l16 = L & 15;
    const size_t tbase = (size_t)b * TT;

    // ---- Q fragments (hi/lo) FIRST: loads issue ahead of zero stores ----
    bf16x8 qfh[2][2], qfl[2][2];             // [rowtile][kchunk]
#pragma unroll
    for (int rt = 0; rt < 2; ++rt)
#pragma unroll
        for (int kc = 0; kc < 2; ++kc) {
            const size_t off = (tbase + Q0 + rt * 16 + l16) * HS + kc * 32 + g * 8;
            qfh[rt][kc] = *reinterpret_cast<const bf16x8*>(qh + off);
            qfl[rt][kc] = *reinterpret_cast<const bf16x8*>(ql + off);
        }

    // ---- early zero-fill of A (cols >= E): drains during QK^T/softmax ----
    {
        f32x4 z;
        z[0] = 0.f; z[1] = 0.f; z[2] = 0.f; z[3] = 0.f;
#pragma unroll
        for (int rr = 0; rr < 4; ++rr) {
            const int row = 4 * w + rr;
            float* arow = A + (tbase + Q0 + row) * TT;
            for (int c0 = (E >> 8) << 8; c0 < TT; c0 += 256) {
                const int col = c0 + 4 * L;
                if (col >= E)
                    *reinterpret_cast<f32x4*>(arow + col) = z;
            }
        }
    }

    // ---- QK^T: pipelined unconditional K-loads, guarded MFMAs ----
    f32x4 acc[16][2];
#pragma unroll
    for (int i = 0; i < 16; ++i)
#pragma unroll
        for (int rt = 0; rt < 2; ++rt)
#pragma unroll
            for (int r = 0; r < 4; ++r) acc[i][rt][r] = 0.f;

    bf16x8 kbh[2][2], kbl[2][2];             // [buf][kchunk]
    {
        const size_t koff = (tbase + w * 16 + l16) * HS + g * 8;
        kbh[0][0] = *reinterpret_cast<const bf16x8*>(kh + koff);
        kbl[0][0] = *reinterpret_cast<const bf16x8*>(kl + koff);
        kbh[0][1] = *reinterpret_cast<const bf16x8*>(kh + koff + 32);
        kbl[0][1] = *reinterpret_cast<const bf16x8*>(kl + koff + 32);
    }
#pragma unroll
    for (int i = 0; i < 16; ++i) {
        const int cur = i & 1, nxt = cur ^ 1;
        if (i < 15) {                        // static guard: prefetch i+1
            const size_t koff =
                (tbase + (w + 8 * (i + 1)) * 16 + l16) * HS + g * 8;
            kbh[nxt][0] = *reinterpret_cast<const bf16x8*>(kh + koff);
            kbl[nxt][0] = *reinterpret_cast<const bf16x8*>(kl + koff);
            kbh[nxt][1] = *reinterpret_cast<const bf16x8*>(kh + koff + 32);
            kbl[nxt][1] = *reinterpret_cast<const bf16x8*>(kl + koff + 32);
        }
        if ((w + 8 * i) * 16 < E) {          // uniform guard: compute only
            __builtin_amdgcn_s_setprio(1);
#pragma unroll
            for (int kc = 0; kc < 2; ++kc)
#pragma unroll
                for (int rt = 0; rt < 2; ++rt) {
                    acc[i][rt] = __builtin_amdgcn_mfma_f32_16x16x32_bf16(
                        qfh[rt][kc], kbh[cur][kc], acc[i][rt], 0, 0, 0);
                    acc[i][rt] = __builtin_amdgcn_mfma_f32_16x16x32_bf16(
                        qfh[rt][kc], kbl[cur][kc], acc[i][rt], 0, 0, 0);
                    acc[i][rt] = __builtin_amdgcn_mfma_f32_16x16x32_bf16(
                        qfl[rt][kc], kbh[cur][kc], acc[i][rt], 0, 0, 0);
                }
            __builtin_amdgcn_s_setprio(0);
        }
    }

    // ---- exp (no max-sub; causal mask -> 0) + partial row sums ----
    float ps[2][4];
#pragma unroll
    for (int rt = 0; rt < 2; ++rt)
#pragma unroll
        for (int r = 0; r < 4; ++r) ps[rt][r] = 0.f;

#pragma unroll
    for (int i = 0; i < 16; ++i) {
        const int k0 = (w + 8 * i) * 16;
        if (k0 < E) {
            const int col = k0 + l16;
#pragma unroll
            for (int rt = 0; rt < 2; ++rt) {
                const int row = Q0 + rt * 16 + g * 4;
#pragma unroll
                for (int r = 0; r < 4; ++r) {
                    const float e =
                        (col > row + r) ? 0.f : __expf(acc[i][rt][r]);
                    acc[i][rt][r] = e;
                    ps[rt][r] += e;
                }
            }
        }
    }
#pragma unroll
    for (int m = 1; m < 16; m <<= 1)
#pragma unroll
        for (int rt = 0; rt < 2; ++rt)
#pragma unroll
            for (int r = 0; r < 4; ++r)
                ps[rt][r] += __shfl_xor(ps[rt][r], m, 64);
    if (l16 == 0)
#pragma unroll
        for (int rt = 0; rt < 2; ++rt)
#pragma unroll
            for (int r = 0; r < 4; ++r)
                reds[w][rt * 16 + g * 4 + r] = ps[rt][r];
    __syncthreads();
    if (tid < 32) {
        float s = 0.f;
#pragma unroll
        for (int ww = 0; ww < 8; ++ww) s += reds[ww][tid];
        sinv[tid] = 1.f / s;
    }
    __syncthreads();
    float iv[2][4];
#pragma unroll
    for (int rt = 0; rt < 2; ++rt)
#pragma unroll
        for (int r = 0; r < 4; ++r) iv[rt][r] = sinv[rt * 16 + g * 4 + r];

    // ---- write A (f32, scattered from regs - spreads store drain) ----
    // ---- + P (bf16, swizzled LDS) in the same loop                 ----
#pragma unroll
    for (int i = 0; i < 16; ++i) {
        const int k0 = (w + 8 * i) * 16;
        if (k0 < E) {
            const int col   = k0 + l16;
            const int chunk = col >> 3;
            const int cl    = col & 7;
#pragma unroll
            for (int rt = 0; rt < 2; ++rt) {
                const int lrow = rt * 16 + g * 4;
#pragma unroll
                for (int r = 0; r < 4; ++r) {
                    const float a = acc[i][rt][r] * iv[rt][r];
                    A[(tbase + Q0 + lrow + r) * TT + col] = a;
                    const int row = lrow + r;
                    P[row * 2048 + ((chunk ^ (row & 7)) << 3) + cl] = f2b(a);
                }
            }
        }
    }
    __syncthreads();

    // ---- PV (last): 2-acc pairs; setprio around MFMAs ----
    const int rt_o = w >> 2;
    const int ht   = w & 3;
    const int prow = rt_o * 16 + l16;
    const unsigned short* vbase = vT + ((size_t)b * HS + ht * 16 + l16) * TT;
    const int nkk = E >> 5;

    f32x4 o0, o1;
#pragma unroll
    for (int r = 0; r < 4; ++r) { o0[r] = 0.f; o1[r] = 0.f; }

    int kk = 0;
    for (; kk + 1 < nkk; kk += 2) {
        const int ch0 = kk * 4 + g;
        const int ch1 = ch0 + 4;
        const bf16x8 pa0 = *reinterpret_cast<const bf16x8*>(
            &P[prow * 2048 + ((ch0 ^ (prow & 7)) << 3)]);
        const bf16x8 pa1 = *reinterpret_cast<const bf16x8*>(
            &P[prow * 2048 + ((ch1 ^ (prow & 7)) << 3)]);
        const bf16x8 vb0 =
            *reinterpret_cast<const bf16x8*>(vbase + kk * 32 + g * 8);
        const bf16x8 vb1 =
            *reinterpret_cast<const bf16x8*>(vbase + (kk + 1) * 32 + g * 8);
        __builtin_amdgcn_s_setprio(1);
        o0 = __builtin_amdgcn_mfma_f32_16x16x32_bf16(pa0, vb0, o0, 0, 0, 0);
        o1 = __builtin_amdgcn_mfma_f32_16x16x32_bf16(pa1, vb1, o1, 0, 0, 0);
        __builtin_amdgcn_s_setprio(0);
    }
    if (kk < nkk) {
        const int ch = kk * 4 + g;
        const bf16x8 pa = *reinterpret_cast<const bf16x8*>(
            &P[prow * 2048 + ((ch ^ (prow & 7)) << 3)]);
        const bf16x8 vb =
            *reinterpret_cast<const bf16x8*>(vbase + kk * 32 + g * 8);
        o0 = __builtin_amdgcn_mfma_f32_16x16x32_bf16(pa, vb, o0, 0, 0, 0);
    }
#pragma unroll
    for (int r = 0; r < 4; ++r) o0[r] += o1[r];

#pragma unroll
    for (int r = 0; r < 4; ++r)
        out[(tbase + Q0 + rt_o * 16 + g * 4 + r) * HS + ht * 16 + l16] =
            o0[r];
}

// ---------------------------------------------------------------------------
extern "C" void kernel_launch(void* const* d_in, const int* in_sizes, int n_in,
                              void* d_out, int out_size, void* d_ws,
                              size_t ws_size, hipStream_t stream)
{
    (void)in_sizes; (void)n_in; (void)out_size; (void)ws_size;

    // setup_inputs() dict order: x, Wk, Wq, Wv
    const float* x  = (const float*)d_in[0];
    const float* Wk = (const float*)d_in[1];
    const float* Wq = (const float*)d_in[2];
    const float* Wv = (const float*)d_in[3];

    float* A   = (float*)d_out;                         // (B,T,T)
    float* out = A + (size_t)BB * TT * TT;              // (B,T,H)

    // workspace: 5 bf16 arrays of B*T*H + W fragments  (10.75 MB total)
    const size_t NTH = (size_t)BB * TT * HS;            // 1048576
    unsigned short* qh  = (unsigned short*)d_ws;
    unsigned short* ql  = qh + NTH;
    unsigned short* kh  = ql + NTH;
    unsigned short* kl  = kh + NTH;
    unsigned short* vT  = kl + NTH;
    unsigned short* whf = vT + NTH;
    unsigned short* wlf = whf + (size_t)24576 * 8;

    wprep_kernel<<<96, 256, 0, stream>>>(Wq, Wk, Wv, whf, wlf);
    proj_mfma<<<512, 256, 0, stream>>>(x, whf, wlf, qh, ql, kh, kl, vT);
    attn_mfma<<<BB * (TT / 32), 512, 0, stream>>>(qh, ql, kh, kl, vT, A, out);
}

// Round 24
// 94.907 us; speedup vs baseline: 1.1266x; 1.1266x over previous
//
#include <hip/hip_runtime.h>
#include <cstdint>
#include <cstddef>

#define NE 1024   // embedding dim
#define HS 64     // head size
#define TT 2048   // sequence length
#define BB 8      // batch

typedef short bf16x8 __attribute__((ext_vector_type(8)));
typedef float f32x4  __attribute__((ext_vector_type(4)));

// round-to-nearest-even f32 -> bf16 (bit pattern as ushort)
__device__ __forceinline__ unsigned short f2b(float f) {
    union { float f; uint32_t u; } v; v.f = f;
    uint32_t r = v.u + 0x7fffu + ((v.u >> 16) & 1u);
    return (unsigned short)(r >> 16);
}
__device__ __forceinline__ float b2f(unsigned short b) {
    union { uint32_t u; float f; } v; v.u = ((uint32_t)b) << 16;
    return v.f;
}

// ---------------------------------------------------------------------------
// Kernel 0: W = [Wq;Wk;Wv*0.125] (192x1024) -> MFMA B-fragments, split hi/lo.
// frag layout (16x16x32): lane L holds B[k=kcg*32+(L>>4)*8+j][col=ntg*16+(L&15)]
// ---------------------------------------------------------------------------
__global__ __launch_bounds__(256) void wprep_kernel(
    const float* __restrict__ Wq, const float* __restrict__ Wk,
    const float* __restrict__ Wv,
    unsigned short* __restrict__ whf, unsigned short* __restrict__ wlf)
{
    const int t   = blockIdx.x * 256 + threadIdx.x;   // 0..24575
    const int L   = t & 63;
    const int kcg = (t >> 6) & 31;
    const int ntg = t >> 11;                          // 0..11
    const int col = ntg * 16 + (L & 15);              // 0..191
    const int k0  = kcg * 32 + (L >> 4) * 8;

    const float* W;
    float scale = 1.f;
    if (col < 64)        W = Wq + (size_t)col * NE;
    else if (col < 128)  W = Wk + (size_t)(col - 64) * NE;
    else               { W = Wv + (size_t)(col - 128) * NE; scale = 0.125f; }

    bf16x8 h, l;
#pragma unroll
    for (int j = 0; j < 8; ++j) {
        const float f = W[k0 + j] * scale;
        const unsigned short hb = f2b(f);
        const unsigned short lb = f2b(f - b2f(hb));
        h[j] = (short)hb;
        l[j] = (short)lb;
    }
    *reinterpret_cast<bf16x8*>(whf + (size_t)t * 8) = h;
    *reinterpret_cast<bf16x8*>(wlf + (size_t)t * 8) = l;
}

// ---------------------------------------------------------------------------
// Kernel 1: projections via split-bf16 MFMA — BK=128 (round-18 champion):
// 8 K-iterations, 16 barrier crossings; each MFMA phase is 72 MFMAs +
// 24 frag loads between syncs. LDS 16 KB; 2 blocks/CU (4 waves/SIMD).
// BM=32, 256 threads = 4 waves, grid 512.
// ---------------------------------------------------------------------------
__global__ __launch_bounds__(256) void proj_mfma(
    const float* __restrict__ x,
    const unsigned short* __restrict__ whf,
    const unsigned short* __restrict__ wlf,
    unsigned short* __restrict__ qh, unsigned short* __restrict__ ql,
    unsigned short* __restrict__ kh, unsigned short* __restrict__ kl,
    unsigned short* __restrict__ vT)
{
    __shared__ unsigned short xh[32 * 128];  // 8 KB, swizzled
    __shared__ unsigned short xl[32 * 128];  // 8 KB, swizzled

    const int tid  = threadIdx.x;
    const int L    = tid & 63;
    const int w    = tid >> 6;               // wave id 0..3
    const int g    = L >> 4;
    const int l16  = L & 15;
    const int row0 = blockIdx.x * 32;
    const int ntgb = w * 3;                  // n-tile-group base: 0,3,6,9

    f32x4 acc[2][3];
#pragma unroll
    for (int mt = 0; mt < 2; ++mt)
#pragma unroll
        for (int nt = 0; nt < 3; ++nt)
#pragma unroll
            for (int r = 0; r < 4; ++r) acc[mt][nt][r] = 0.f;

    // staging: 32x128 tile = 512 8-float chunks; thread covers chunks
    // c = tid, tid+256 -> row = c>>4, col8 = c&15 (coalesced float4 pairs)
    const int srow0 = tid >> 4;              // 0..15  (chunk tid)
    const int scol0 = tid & 15;
    const int srow1 = (tid + 256) >> 4;      // 16..31 (chunk tid+256)
    const int scol1 = scol0;
    const float* xsrc0 = x + (size_t)(row0 + srow0) * NE + scol0 * 8;
    const float* xsrc1 = x + (size_t)(row0 + srow1) * NE + scol1 * 8;
    const int soff0 = srow0 * 128 + ((scol0 ^ (srow0 & 7)) << 3);
    const int soff1 = srow1 * 128 + ((scol1 ^ (srow1 & 7)) << 3);

    // prefetch ks = 0
    float4 p0 = *reinterpret_cast<const float4*>(xsrc0);
    float4 p1 = *reinterpret_cast<const float4*>(xsrc0 + 4);
    float4 p2 = *reinterpret_cast<const float4*>(xsrc1);
    float4 p3 = *reinterpret_cast<const float4*>(xsrc1 + 4);

    for (int ks = 0; ks < 8; ++ks) {         // K loop, BK = 128
        __syncthreads();                     // prior-step LDS reads done
        {
            float xv[8];
            bf16x8 hv, lv;
            xv[0]=p0.x; xv[1]=p0.y; xv[2]=p0.z; xv[3]=p0.w;
            xv[4]=p1.x; xv[5]=p1.y; xv[6]=p1.z; xv[7]=p1.w;
#pragma unroll
            for (int j = 0; j < 8; ++j) {
                const unsigned short hb = f2b(xv[j]);
                const unsigned short lb = f2b(xv[j] - b2f(hb));
                hv[j] = (short)hb; lv[j] = (short)lb;
            }
            *reinterpret_cast<bf16x8*>(&xh[soff0]) = hv;
            *reinterpret_cast<bf16x8*>(&xl[soff0]) = lv;
            xv[0]=p2.x; xv[1]=p2.y; xv[2]=p2.z; xv[3]=p2.w;
            xv[4]=p3.x; xv[5]=p3.y; xv[6]=p3.z; xv[7]=p3.w;
#pragma unroll
            for (int j = 0; j < 8; ++j) {
                const unsigned short hb = f2b(xv[j]);
                const unsigned short lb = f2b(xv[j] - b2f(hb));
                hv[j] = (short)hb; lv[j] = (short)lb;
            }
            *reinterpret_cast<bf16x8*>(&xh[soff1]) = hv;
            *reinterpret_cast<bf16x8*>(&xl[soff1]) = lv;
        }
        if (ks < 7) {                        // prefetch next subtile
            p0 = *reinterpret_cast<const float4*>(xsrc0 + (ks + 1) * 128);
            p1 = *reinterpret_cast<const float4*>(xsrc0 + (ks + 1) * 128 + 4);
            p2 = *reinterpret_cast<const float4*>(xsrc1 + (ks + 1) * 128);
            p3 = *reinterpret_cast<const float4*>(xsrc1 + (ks + 1) * 128 + 4);
        }
        __syncthreads();

#pragma unroll
        for (int kc = 0; kc < 4; ++kc) {     // four K=32 chunks per step
            bf16x8 ah[2], al[2];
#pragma unroll
            for (int mt = 0; mt < 2; ++mt) {
                const int r    = mt * 16 + l16;
                const int kb16 = kc * 4 + g;
                const int off  = r * 128 + ((kb16 ^ (r & 7)) << 3);
                ah[mt] = *reinterpret_cast<const bf16x8*>(&xh[off]);
                al[mt] = *reinterpret_cast<const bf16x8*>(&xl[off]);
            }
#pragma unroll
            for (int nt = 0; nt < 3; ++nt) {
                const size_t fidx =
                    ((size_t)((ntgb + nt) * 32 + (ks * 4 + kc))) * 64 + L;
                const bf16x8 bh = *reinterpret_cast<const bf16x8*>(whf + fidx * 8);
                const bf16x8 bl = *reinterpret_cast<const bf16x8*>(wlf + fidx * 8);
#pragma unroll
                for (int mt = 0; mt < 2; ++mt) {
                    acc[mt][nt] = __builtin_amdgcn_mfma_f32_16x16x32_bf16(
                        ah[mt], bh, acc[mt][nt], 0, 0, 0);
                    acc[mt][nt] = __builtin_amdgcn_mfma_f32_16x16x32_bf16(
                        ah[mt], bl, acc[mt][nt], 0, 0, 0);
                    acc[mt][nt] = __builtin_amdgcn_mfma_f32_16x16x32_bf16(
                        al[mt], bh, acc[mt][nt], 0, 0, 0);
                }
            }
        }
    }

    // epilogue: C/D layout col=L&15, row=(L>>4)*4+reg
#pragma unroll
    for (int nt = 0; nt < 3; ++nt) {
        const int gc0 = (ntgb + nt) * 16;
        const int lc  = l16;
#pragma unroll
        for (int mt = 0; mt < 2; ++mt) {
            const int t0g = row0 + mt * 16 + g * 4;   // row of reg 0
            if (gc0 < 128) {
                unsigned short* dh = (gc0 < 64) ? qh : kh;
                unsigned short* dl = (gc0 < 64) ? ql : kl;
                const int col = (gc0 & 63) + lc;
#pragma unroll
                for (int reg = 0; reg < 4; ++reg) {
                    const float val = acc[mt][nt][reg];
                    const unsigned short hb = f2b(val);
                    const unsigned short lb = f2b(val - b2f(hb));
                    dh[(size_t)(t0g + reg) * HS + col] = hb;
                    dl[(size_t)(t0g + reg) * HS + col] = lb;
                }
            } else {
                const int col  = (gc0 - 128) + lc;   // h index
                const int bat  = t0g >> 11;
                const int tloc = t0g & 2047;
                ushort4 pk;
                unsigned short* pp = reinterpret_cast<unsigned short*>(&pk);
#pragma unroll
                for (int reg = 0; reg < 4; ++reg)
                    pp[reg] = f2b(acc[mt][nt][reg]);
                *reinterpret_cast<ushort4*>(
                    &vT[((size_t)bat * HS + col) * TT + tloc]) = pk;
            }
        }
    }
}

// ---------------------------------------------------------------------------
// Kernel 2: MFMA causal attention — round-21 champion (final):
// QBLK=32, 512 thr = 8 waves, descending qt (LPT), no max-sub, Q-frag
// loads hoisted before the early zero-fill, scattered A stores fused with
// P-write, PV last with 2 alternating accumulators, setprio around MFMAs.
// ---------------------------------------------------------------------------
__global__ __launch_bounds__(512, 2) void attn_mfma(
    const unsigned short* __restrict__ qh, const unsigned short* __restrict__ ql,
    const unsigned short* __restrict__ kh, const unsigned short* __restrict__ kl,
    const unsigned short* __restrict__ vT,
    float* __restrict__ A, float* __restrict__ out)
{
    __shared__ unsigned short P[32 * TT];    // 128 KB, 16B-chunk XOR swizzle
    __shared__ float reds[8][32];
    __shared__ float sinv[32];

    const int tid = threadIdx.x;
    const int L   = tid & 63;
    const int w   = tid >> 6;                // wave 0..7
    const int b   = blockIdx.x & 7;          // batch == XCD slot
    const int qt  = 63 - (blockIdx.x >> 3);  // longest first (LPT)
    const int Q0  = qt * 32;
    const int E   = Q0 + 32;                 // causal extent (mult of 32)
    const int g   = L >> 4;
    const int l16 = L & 15;
    const size_t tbase = (size_t)b * TT;

    // ---- Q fragments (hi/lo) FIRST: loads issue ahead of zero stores ----
    bf16x8 qfh[2][2], qfl[2][2];             // [rowtile][kchunk]
#pragma unroll
    for (int rt = 0; rt < 2; ++rt)
#pragma unroll
        for (int kc = 0; kc < 2; ++kc) {
            const size_t off = (tbase + Q0 + rt * 16 + l16) * HS + kc * 32 + g * 8;
            qfh[rt][kc] = *reinterpret_cast<const bf16x8*>(qh + off);
            qfl[rt][kc] = *reinterpret_cast<const bf16x8*>(ql + off);
        }

    // ---- early zero-fill of A (cols >= E): drains during QK^T/softmax ----
    {
        f32x4 z;
        z[0] = 0.f; z[1] = 0.f; z[2] = 0.f; z[3] = 0.f;
#pragma unroll
        for (int rr = 0; rr < 4; ++rr) {
            const int row = 4 * w + rr;
            float* arow = A + (tbase + Q0 + row) * TT;
            for (int c0 = (E >> 8) << 8; c0 < TT; c0 += 256) {
                const int col = c0 + 4 * L;
                if (col >= E)
                    *reinterpret_cast<f32x4*>(arow + col) = z;
            }
        }
    }

    // ---- QK^T (split bf16: hh + hl + lh), guarded; setprio on MFMA ----
    f32x4 acc[16][2];
#pragma unroll
    for (int i = 0; i < 16; ++i)
#pragma unroll
        for (int rt = 0; rt < 2; ++rt)
#pragma unroll
            for (int r = 0; r < 4; ++r) acc[i][rt][r] = 0.f;

#pragma unroll
    for (int i = 0; i < 16; ++i) {
        const int k0 = (w + 8 * i) * 16;
        if (k0 < E) {
#pragma unroll
            for (int kc = 0; kc < 2; ++kc) {
                const size_t koff = (tbase + k0 + l16) * HS + kc * 32 + g * 8;
                const bf16x8 bh = *reinterpret_cast<const bf16x8*>(kh + koff);
                const bf16x8 bl = *reinterpret_cast<const bf16x8*>(kl + koff);
                __builtin_amdgcn_s_setprio(1);
#pragma unroll
                for (int rt = 0; rt < 2; ++rt) {
                    acc[i][rt] = __builtin_amdgcn_mfma_f32_16x16x32_bf16(
                        qfh[rt][kc], bh, acc[i][rt], 0, 0, 0);
                    acc[i][rt] = __builtin_amdgcn_mfma_f32_16x16x32_bf16(
                        qfh[rt][kc], bl, acc[i][rt], 0, 0, 0);
                    acc[i][rt] = __builtin_amdgcn_mfma_f32_16x16x32_bf16(
                        qfl[rt][kc], bh, acc[i][rt], 0, 0, 0);
                }
                __builtin_amdgcn_s_setprio(0);
            }
        }
    }

    // ---- exp (no max-sub; causal mask -> 0) + partial row sums ----
    float ps[2][4];
#pragma unroll
    for (int rt = 0; rt < 2; ++rt)
#pragma unroll
        for (int r = 0; r < 4; ++r) ps[rt][r] = 0.f;

#pragma unroll
    for (int i = 0; i < 16; ++i) {
        const int k0 = (w + 8 * i) * 16;
        if (k0 < E) {
            const int col = k0 + l16;
#pragma unroll
            for (int rt = 0; rt < 2; ++rt) {
                const int row = Q0 + rt * 16 + g * 4;
#pragma unroll
                for (int r = 0; r < 4; ++r) {
                    const float e =
                        (col > row + r) ? 0.f : __expf(acc[i][rt][r]);
                    acc[i][rt][r] = e;
                    ps[rt][r] += e;
                }
            }
        }
    }
#pragma unroll
    for (int m = 1; m < 16; m <<= 1)
#pragma unroll
        for (int rt = 0; rt < 2; ++rt)
#pragma unroll
            for (int r = 0; r < 4; ++r)
                ps[rt][r] += __shfl_xor(ps[rt][r], m, 64);
    if (l16 == 0)
#pragma unroll
        for (int rt = 0; rt < 2; ++rt)
#pragma unroll
            for (int r = 0; r < 4; ++r)
                reds[w][rt * 16 + g * 4 + r] = ps[rt][r];
    __syncthreads();
    if (tid < 32) {
        float s = 0.f;
#pragma unroll
        for (int ww = 0; ww < 8; ++ww) s += reds[ww][tid];
        sinv[tid] = 1.f / s;
    }
    __syncthreads();
    float iv[2][4];
#pragma unroll
    for (int rt = 0; rt < 2; ++rt)
#pragma unroll
        for (int r = 0; r < 4; ++r) iv[rt][r] = sinv[rt * 16 + g * 4 + r];

    // ---- write A (f32, scattered from regs - spreads store drain) ----
    // ---- + P (bf16, swizzled LDS) in the same loop                 ----
#pragma unroll
    for (int i = 0; i < 16; ++i) {
        const int k0 = (w + 8 * i) * 16;
        if (k0 < E) {
            const int col   = k0 + l16;
            const int chunk = col >> 3;
            const int cl    = col & 7;
#pragma unroll
            for (int rt = 0; rt < 2; ++rt) {
                const int lrow = rt * 16 + g * 4;
#pragma unroll
                for (int r = 0; r < 4; ++r) {
                    const float a = acc[i][rt][r] * iv[rt][r];
                    A[(tbase + Q0 + lrow + r) * TT + col] = a;
                    const int row = lrow + r;
                    P[row * 2048 + ((chunk ^ (row & 7)) << 3) + cl] = f2b(a);
                }
            }
        }
    }
    __syncthreads();

    // ---- PV (last): 2-acc pairs; setprio around MFMAs ----
    const int rt_o = w >> 2;
    const int ht   = w & 3;
    const int prow = rt_o * 16 + l16;
    const unsigned short* vbase = vT + ((size_t)b * HS + ht * 16 + l16) * TT;
    const int nkk = E >> 5;

    f32x4 o0, o1;
#pragma unroll
    for (int r = 0; r < 4; ++r) { o0[r] = 0.f; o1[r] = 0.f; }

    int kk = 0;
    for (; kk + 1 < nkk; kk += 2) {
        const int ch0 = kk * 4 + g;
        const int ch1 = ch0 + 4;
        const bf16x8 pa0 = *reinterpret_cast<const bf16x8*>(
            &P[prow * 2048 + ((ch0 ^ (prow & 7)) << 3)]);
        const bf16x8 pa1 = *reinterpret_cast<const bf16x8*>(
            &P[prow * 2048 + ((ch1 ^ (prow & 7)) << 3)]);
        const bf16x8 vb0 =
            *reinterpret_cast<const bf16x8*>(vbase + kk * 32 + g * 8);
        const bf16x8 vb1 =
            *reinterpret_cast<const bf16x8*>(vbase + (kk + 1) * 32 + g * 8);
        __builtin_amdgcn_s_setprio(1);
        o0 = __builtin_amdgcn_mfma_f32_16x16x32_bf16(pa0, vb0, o0, 0, 0, 0);
        o1 = __builtin_amdgcn_mfma_f32_16x16x32_bf16(pa1, vb1, o1, 0, 0, 0);
        __builtin_amdgcn_s_setprio(0);
    }
    if (kk < nkk) {
        const int ch = kk * 4 + g;
        const bf16x8 pa = *reinterpret_cast<const bf16x8*>(
            &P[prow * 2048 + ((ch ^ (prow & 7)) << 3)]);
        const bf16x8 vb =
            *reinterpret_cast<const bf16x8*>(vbase + kk * 32 + g * 8);
        o0 = __builtin_amdgcn_mfma_f32_16x16x32_bf16(pa, vb, o0, 0, 0, 0);
    }
#pragma unroll
    for (int r = 0; r < 4; ++r) o0[r] += o1[r];

#pragma unroll
    for (int r = 0; r < 4; ++r)
        out[(tbase + Q0 + rt_o * 16 + g * 4 + r) * HS + ht * 16 + l16] =
            o0[r];
}

// ---------------------------------------------------------------------------
extern "C" void kernel_launch(void* const* d_in, const int* in_sizes, int n_in,
                              void* d_out, int out_size, void* d_ws,
                              size_t ws_size, hipStream_t stream)
{
    (void)in_sizes; (void)n_in; (void)out_size; (void)ws_size;

    // setup_inputs() dict order: x, Wk, Wq, Wv
    const float* x  = (const float*)d_in[0];
    const float* Wk = (const float*)d_in[1];
    const float* Wq = (const float*)d_in[2];
    const float* Wv = (const float*)d_in[3];

    float* A   = (float*)d_out;                         // (B,T,T)
    float* out = A + (size_t)BB * TT * TT;              // (B,T,H)

    // workspace: 5 bf16 arrays of B*T*H + W fragments  (10.75 MB total)
    const size_t NTH = (size_t)BB * TT * HS;            // 1048576
    unsigned short* qh  = (unsigned short*)d_ws;
    unsigned short* ql  = qh + NTH;
    unsigned short* kh  = ql + NTH;
    unsigned short* kl  = kh + NTH;
    unsigned short* vT  = kl + NTH;
    unsigned short* whf = vT + NTH;
    unsigned short* wlf = whf + (size_t)24576 * 8;

    wprep_kernel<<<96, 256, 0, stream>>>(Wq, Wk, Wv, whf, wlf);
    proj_mfma<<<512, 256, 0, stream>>>(x, whf, wlf, qh, ql, kh, kl, vT);
    attn_mfma<<<BB * (TT / 32), 512, 0, stream>>>(qh, ql, kh, kl, vT, A, out);
}